// Round 4
// baseline (54.845 us; speedup 1.0000x reference)
//
#include <hip/hip_runtime.h>
#include <math.h>

// Split design:
//  Kernel A (gram_kernel): streaming phase. One item per 8-lane group
//    (8 items/wave, 32/block). fp64 Gram accumulation (15 dots, 16 dims/lane),
//    3-stage reduce-scatter over the group (14 f64 shuffles, static indices),
//    each lane stores its 2 owned sums to d_ws (SoA planes, padded stride).
//    Low VGPR -> 6+ waves/SIMD -> enough loads in flight to saturate HBM.
//  Kernel B (finish_kernel): one item per lane, reads g[15] coalesced from
//    d_ws, computes edge stats, spread, det(W) 4x4 LU (det M6 = -16 det W,
//    vol^2 = det W / 576), sigmoids, Cantor chain. fp64 throughout.
//  Fallback fused kernel if ws_size is too small.

__device__ __forceinline__ constexpr int gidx(int i, int j) {
    return i * 5 - i * (i - 1) / 2 + (j - i);   // upper-tri (i<=j) -> [0,15)
}

// ---------------------------------------------------------------- kernel A
__global__ __launch_bounds__(256, 6) void gram_kernel(
    const float* __restrict__ pent, double* __restrict__ ws,
    int nItems, int Np)
{
    const int tid  = threadIdx.x;
    const int wave = tid >> 6;
    const int lane = tid & 63;
    const int grp  = lane >> 3;
    const int s    = lane & 7;

    long item  = (long)blockIdx.x * 32 + (long)wave * 8 + grp;
    long itemC = item < nItems ? item : (long)nItems - 1;

    const float4* __restrict__ p =
        reinterpret_cast<const float4*>(pent + itemC * 640L);

    // 20 x global_load_dwordx4; per (v,j) instruction lanes s=0..7 cover a
    // contiguous 128B chunk per item -> fully coalesced.
    float4 f[5][4];
#pragma unroll
    for (int v = 0; v < 5; ++v)
#pragma unroll
        for (int j = 0; j < 4; ++j)
            f[v][j] = p[v * 32 + j * 8 + s];

    const float* fp = reinterpret_cast<const float*>(f);

    double g[16];
#pragma unroll
    for (int q = 0; q < 16; ++q) g[q] = 0.0;

#pragma unroll
    for (int t = 0; t < 16; ++t) {
        double a[5];
#pragma unroll
        for (int v = 0; v < 5; ++v)
            a[v] = (double)fp[v * 16 + t];
        int q = 0;
#pragma unroll
        for (int i = 0; i < 5; ++i)
#pragma unroll
            for (int j = i; j < 5; ++j) {
                g[q] = fma(a[i], a[j], g[q]);
                ++q;
            }
    }

    // 3-stage reduce-scatter within the 8-lane group. Static indices only;
    // lane-dependent choice is on VALUES (ternary), never on indices.
    {
        const bool b = (s & 1) != 0;
#pragma unroll
        for (int i = 0; i < 8; ++i) {
            double lo = g[i], hi = g[i + 8];
            double recv = __shfl_xor(b ? lo : hi, 1, 64);
            g[i] = (b ? hi : lo) + recv;
        }
    }
    {
        const bool b = (s & 2) != 0;
#pragma unroll
        for (int i = 0; i < 4; ++i) {
            double lo = g[i], hi = g[i + 4];
            double recv = __shfl_xor(b ? lo : hi, 2, 64);
            g[i] = (b ? hi : lo) + recv;
        }
    }
    {
        const bool b = (s & 4) != 0;
#pragma unroll
        for (int i = 0; i < 2; ++i) {
            double lo = g[i], hi = g[i + 2];
            double recv = __shfl_xor(b ? lo : hi, 4, 64);
            g[i] = (b ? hi : lo) + recv;
        }
    }
    // lane s owns sums {k, k+1}, k = 8*b0 + 4*b1 + 2*b2
    const int k = ((s & 1) << 3) | ((s & 2) << 1) | ((s & 4) >> 1);

    if (item < nItems) {
        ws[(long)k * Np + item]       = g[0];
        ws[(long)(k + 1) * Np + item] = g[1];
    }
}

// ---------------------------------------------------------------- kernel B
__global__ __launch_bounds__(256) void finish_kernel(
    const double* __restrict__ ws, float* __restrict__ out,
    int nItems, int Np)
{
    const long item = (long)blockIdx.x * 256 + threadIdx.x;
    if (item >= nItems) return;

    double h[15];
#pragma unroll
    for (int q = 0; q < 15; ++q)
        h[q] = ws[(long)q * Np + item];

    // Edge statistics over the 10 pairwise distances (ddof=1).
    double e[10], se = 0.0;
    {
        int q = 0;
#pragma unroll
        for (int i = 0; i < 5; ++i)
#pragma unroll
            for (int j = i + 1; j < 5; ++j) {
                double d2 = fma(-2.0, h[gidx(i, j)],
                                h[gidx(i, i)] + h[gidx(j, j)]);
                e[q] = sqrt(d2);
                se += e[q];
                ++q;
            }
    }
    double meanE = se * 0.1;
    double ve = 0.0;
#pragma unroll
    for (int q = 0; q < 10; ++q) { double d = e[q] - meanE; ve = fma(d, d, ve); }
    double stdE = sqrt(ve / 9.0);

    // Row sums and total.
    double S[5], T = 0.0;
#pragma unroll
    for (int i = 0; i < 5; ++i) {
        double si = 0.0;
#pragma unroll
        for (int j = 0; j < 5; ++j) {
            int a = i < j ? i : j;
            int b = i < j ? j : i;
            si += h[gidx(a, b)];
        }
        S[i] = si;
        T += si;
    }

    // Vertex spread (ddof=1 over 5 centroid distances).
    double scd = 0.0, cd[5];
#pragma unroll
    for (int v = 0; v < 5; ++v) {
        double c2 = fma(-0.4, S[v], h[gidx(v, v)]) + 0.04 * T;
        cd[v] = (c2 > 0.0) ? sqrt(c2) : 0.0;
        scd += cd[v];
    }
    double meanC = scd * 0.2;
    double vc = 0.0;
#pragma unroll
    for (int v = 0; v < 5; ++v) { double d = cd[v] - meanC; vc = fma(d, d, vc); }
    double spread = sqrt(vc * 0.25);

    // W[pq] = (x_p-x_0)·(x_q-x_0), p,q in 1..4 (PSD). vol^2 = det W / 576.
    double W[4][4];
#pragma unroll
    for (int pi = 0; pi < 4; ++pi)
#pragma unroll
        for (int qi = 0; qi < 4; ++qi) {
            int lo = (pi < qi ? pi : qi) + 1;
            int hi = (pi < qi ? qi : pi) + 1;
            W[pi][qi] = h[gidx(lo, hi)] - h[gidx(0, qi + 1)]
                      - h[gidx(0, pi + 1)] + h[gidx(0, 0)];
        }

    double det = 1.0;
#pragma unroll
    for (int kk = 0; kk < 4; ++kk) {
        double pv = W[kk][kk];
        det *= pv;
        double inv = (pv != 0.0) ? 1.0 / pv : 0.0;
#pragma unroll
        for (int r = kk + 1; r < 4; ++r) {
            double fac = W[r][kk] * inv;
#pragma unroll
            for (int c = kk + 1; c < 4; ++c)
                W[r][c] = fma(-fac, W[kk][c], W[r][c]);
        }
    }

    double v2 = det / 576.0;
    double volume = (v2 > 0.0) ? sqrt(v2) : 0.0;

    double vn = 1.0 / (1.0 + exp(-10.0 * volume));
    double er = 1.0 / (1.0 + exp(-(stdE / (meanE + 1e-6))));
    double sn = 1.0 / (1.0 + exp(-spread));

    double seed = 0.4 * vn + 0.3 * er + 0.3 * sn;
    seed = fmin(fmax(seed, 1e-6), 1.0 - 1e-6);
    double drift = (vn + er + sn) * 0.01;

    double x = seed, cv = 0.0, factor = 0.5;
#pragma unroll
    for (int kk = 0; kk < 8; ++kk) {
        double xs = x * 3.0;
        double dg = floor(xs);
        double fr = xs - dg;
        cv += (dg == 2.0) ? factor : 0.0;
        factor *= 0.5;
        x = fmin(fmax(fr + drift, 1e-6), 1.0 - 1e-6);
    }
    cv = fmin(fmax(cv, 0.0), 1.0);

    out[item] = (float)cv;
}

// ------------------------------------------------- fallback fused (R3) path
__global__ __launch_bounds__(256, 4) void fused_kernel(
    const float* __restrict__ pent, float* __restrict__ out, int nItems)
{
    __shared__ double lds_g[32][15];

    const int tid  = threadIdx.x;
    const int wave = tid >> 6;
    const int lane = tid & 63;
    const int grp  = lane >> 3;
    const int s    = lane & 7;

    long item  = (long)blockIdx.x * 32 + (long)wave * 8 + grp;
    long itemC = item < nItems ? item : (long)nItems - 1;

    const float4* __restrict__ p =
        reinterpret_cast<const float4*>(pent + itemC * 640L);

    float4 f[5][4];
#pragma unroll
    for (int v = 0; v < 5; ++v)
#pragma unroll
        for (int j = 0; j < 4; ++j)
            f[v][j] = p[v * 32 + j * 8 + s];

    const float* fp = reinterpret_cast<const float*>(f);

    double g[15];
#pragma unroll
    for (int q = 0; q < 15; ++q) g[q] = 0.0;

#pragma unroll
    for (int t = 0; t < 16; ++t) {
        double a[5];
#pragma unroll
        for (int v = 0; v < 5; ++v)
            a[v] = (double)fp[v * 16 + t];
        int q = 0;
#pragma unroll
        for (int i = 0; i < 5; ++i)
#pragma unroll
            for (int j = i; j < 5; ++j) {
                g[q] = fma(a[i], a[j], g[q]);
                ++q;
            }
    }

#pragma unroll
    for (int m = 1; m <= 4; m <<= 1)
#pragma unroll
        for (int q = 0; q < 15; ++q) g[q] += __shfl_xor(g[q], m, 64);

    if (s == 0) {
        const int slot = wave * 8 + grp;
#pragma unroll
        for (int q = 0; q < 15; ++q) lds_g[slot][q] = g[q];
    }
    __syncthreads();

    if (tid < 32) {
        const long item2 = (long)blockIdx.x * 32 + tid;

        double h[15];
#pragma unroll
        for (int q = 0; q < 15; ++q) h[q] = lds_g[tid][q];

        double e[10], se = 0.0;
        {
            int q = 0;
#pragma unroll
            for (int i = 0; i < 5; ++i)
#pragma unroll
                for (int j = i + 1; j < 5; ++j) {
                    double d2 = fma(-2.0, h[gidx(i, j)],
                                    h[gidx(i, i)] + h[gidx(j, j)]);
                    e[q] = sqrt(d2);
                    se += e[q];
                    ++q;
                }
        }
        double meanE = se * 0.1;
        double ve = 0.0;
#pragma unroll
        for (int q = 0; q < 10; ++q) { double d = e[q] - meanE; ve = fma(d, d, ve); }
        double stdE = sqrt(ve / 9.0);

        double S[5], T = 0.0;
#pragma unroll
        for (int i = 0; i < 5; ++i) {
            double si = 0.0;
#pragma unroll
            for (int j = 0; j < 5; ++j) {
                int a = i < j ? i : j;
                int b = i < j ? j : i;
                si += h[gidx(a, b)];
            }
            S[i] = si;
            T += si;
        }

        double scd = 0.0, cd[5];
#pragma unroll
        for (int v = 0; v < 5; ++v) {
            double c2 = fma(-0.4, S[v], h[gidx(v, v)]) + 0.04 * T;
            cd[v] = (c2 > 0.0) ? sqrt(c2) : 0.0;
            scd += cd[v];
        }
        double meanC = scd * 0.2;
        double vc = 0.0;
#pragma unroll
        for (int v = 0; v < 5; ++v) { double d = cd[v] - meanC; vc = fma(d, d, vc); }
        double spread = sqrt(vc * 0.25);

        double W[4][4];
#pragma unroll
        for (int pi = 0; pi < 4; ++pi)
#pragma unroll
            for (int qi = 0; qi < 4; ++qi) {
                int lo = (pi < qi ? pi : qi) + 1;
                int hi = (pi < qi ? qi : pi) + 1;
                W[pi][qi] = h[gidx(lo, hi)] - h[gidx(0, qi + 1)]
                          - h[gidx(0, pi + 1)] + h[gidx(0, 0)];
            }

        double det = 1.0;
#pragma unroll
        for (int kk = 0; kk < 4; ++kk) {
            double pv = W[kk][kk];
            det *= pv;
            double inv = (pv != 0.0) ? 1.0 / pv : 0.0;
#pragma unroll
            for (int r = kk + 1; r < 4; ++r) {
                double fac = W[r][kk] * inv;
#pragma unroll
                for (int c = kk + 1; c < 4; ++c)
                    W[r][c] = fma(-fac, W[kk][c], W[r][c]);
            }
        }

        double v2 = det / 576.0;
        double volume = (v2 > 0.0) ? sqrt(v2) : 0.0;

        double vn = 1.0 / (1.0 + exp(-10.0 * volume));
        double er = 1.0 / (1.0 + exp(-(stdE / (meanE + 1e-6))));
        double sn = 1.0 / (1.0 + exp(-spread));

        double seed = 0.4 * vn + 0.3 * er + 0.3 * sn;
        seed = fmin(fmax(seed, 1e-6), 1.0 - 1e-6);
        double drift = (vn + er + sn) * 0.01;

        double x = seed, cv = 0.0, factor = 0.5;
#pragma unroll
        for (int kk = 0; kk < 8; ++kk) {
            double xs = x * 3.0;
            double dg = floor(xs);
            double fr = xs - dg;
            cv += (dg == 2.0) ? factor : 0.0;
            factor *= 0.5;
            x = fmin(fmax(fr + drift, 1e-6), 1.0 - 1e-6);
        }
        cv = fmin(fmax(cv, 0.0), 1.0);

        if (item2 < nItems)
            out[item2] = (float)cv;
    }
}

extern "C" void kernel_launch(void* const* d_in, const int* in_sizes, int n_in,
                              void* d_out, int out_size, void* d_ws, size_t ws_size,
                              hipStream_t stream) {
    const float* pent = (const float*)d_in[0];
    float* out = (float*)d_out;
    int nItems = in_sizes[0] / 640;                 // 5*128 floats per item
    int Np = (nItems + 255) & ~255;                 // padded SoA plane stride
    size_t need = (size_t)16 * (size_t)Np * sizeof(double);

    if (ws_size >= need) {
        double* ws = (double*)d_ws;
        int blocksA = (nItems + 31) / 32;           // 32 items / 256-thread block
        hipLaunchKernelGGL(gram_kernel, dim3(blocksA), dim3(256), 0, stream,
                           pent, ws, nItems, Np);
        int blocksB = (nItems + 255) / 256;
        hipLaunchKernelGGL(finish_kernel, dim3(blocksB), dim3(256), 0, stream,
                           ws, out, nItems, Np);
    } else {
        int blocks = (nItems + 31) / 32;
        hipLaunchKernelGGL(fused_kernel, dim3(blocks), dim3(256), 0, stream,
                           pent, out, nItems);
    }
}

// Round 6
// 44.642 us; speedup vs baseline: 1.2285x; 1.2285x over previous
//
#include <hip/hip_runtime.h>
#include <math.h>

// R3 structure (fused, proven 45.1us) + non-temporal staging loads via
// native ext_vector_type(4) float (HIP's float4 class is rejected by
// __builtin_nontemporal_load).
// Phase 1: one item per 8-lane group (8 items/wave, 32/block). fp64 Gram
//          accumulation (15 dots), 16 dims/lane, butterfly reduce (1,2,4).
//          Group lane 0 writes g[15] to LDS.
// Phase 2: ONE wave per block, one item per lane (32 lanes active): reads
//          g[15] from LDS, edge stats, spread, det(W) via 4x4 LU
//          (det M6 = -16 det W, vol^2 = det W/576), sigmoids, Cantor chain.
// All math fp64 (Cantor map amplifies seed error ~3^8; need ~1e-9 seed acc).

typedef float f32x4 __attribute__((ext_vector_type(4)));

__device__ __forceinline__ constexpr int gidx(int i, int j) {
    return i * 5 - i * (i - 1) / 2 + (j - i);   // upper-tri (i<=j) -> [0,15)
}

__global__ __launch_bounds__(256, 4) void fingerprint_kernel(
    const float* __restrict__ pent, float* __restrict__ out, int nItems)
{
    __shared__ double lds_g[32][15];   // 3840 B; stride 120 B

    const int tid  = threadIdx.x;
    const int wave = tid >> 6;
    const int lane = tid & 63;
    const int grp  = lane >> 3;   // which of the wave's 8 items
    const int s    = lane & 7;    // slice within the item

    long item  = (long)blockIdx.x * 32 + (long)wave * 8 + grp;
    long itemC = item < nItems ? item : (long)nItems - 1;

    const f32x4* __restrict__ p =
        reinterpret_cast<const f32x4*>(pent + itemC * 640L);

    // 20 x global_load_dwordx4 (nt); per (v,j) instruction lanes s=0..7 cover
    // a contiguous 128B chunk per item -> fully coalesced. Non-temporal:
    // stream is read exactly once, skip cache allocation.
    f32x4 f[5][4];
#pragma unroll
    for (int v = 0; v < 5; ++v)
#pragma unroll
        for (int j = 0; j < 4; ++j)
            f[v][j] = __builtin_nontemporal_load(&p[v * 32 + j * 8 + s]);

    const float* fp = reinterpret_cast<const float*>(f);

    double g[15];
#pragma unroll
    for (int q = 0; q < 15; ++q) g[q] = 0.0;

#pragma unroll
    for (int t = 0; t < 16; ++t) {           // this lane's 16 dims
        double a[5];
#pragma unroll
        for (int v = 0; v < 5; ++v)
            a[v] = (double)fp[v * 16 + t];
        int q = 0;
#pragma unroll
        for (int i = 0; i < 5; ++i)
#pragma unroll
            for (int j = i; j < 5; ++j) {
                g[q] = fma(a[i], a[j], g[q]);
                ++q;
            }
    }

    // Butterfly reduce within the 8-lane group.
#pragma unroll
    for (int m = 1; m <= 4; m <<= 1)
#pragma unroll
        for (int q = 0; q < 15; ++q) g[q] += __shfl_xor(g[q], m, 64);

    // Hand off to LDS (one writer per group; static q indices only).
    if (s == 0) {
        const int slot = wave * 8 + grp;
#pragma unroll
        for (int q = 0; q < 15; ++q) lds_g[slot][q] = g[q];
    }
    __syncthreads();

    // ---- Phase 2: one wave, one item per lane ----
    if (tid < 32) {
        const long item2 = (long)blockIdx.x * 32 + tid;

        double h[15];
#pragma unroll
        for (int q = 0; q < 15; ++q) h[q] = lds_g[tid][q];

        // Edge statistics over the 10 pairwise distances (ddof=1).
        double e[10];
        double se = 0.0;
        {
            int q = 0;
#pragma unroll
            for (int i = 0; i < 5; ++i)
#pragma unroll
                for (int j = i + 1; j < 5; ++j) {
                    double d2 = fma(-2.0, h[gidx(i, j)],
                                    h[gidx(i, i)] + h[gidx(j, j)]);
                    e[q] = sqrt(d2);
                    se += e[q];
                    ++q;
                }
        }
        double meanE = se * 0.1;
        double ve = 0.0;
#pragma unroll
        for (int q = 0; q < 10; ++q) {
            double d = e[q] - meanE;
            ve = fma(d, d, ve);
        }
        double stdE = sqrt(ve / 9.0);

        // Row sums S[i] = sum_j G[i][j], total T.
        double S[5], T = 0.0;
#pragma unroll
        for (int i = 0; i < 5; ++i) {
            double si = 0.0;
#pragma unroll
            for (int j = 0; j < 5; ++j) {
                int a = i < j ? i : j;
                int b = i < j ? j : i;
                si += h[gidx(a, b)];
            }
            S[i] = si;
            T += si;
        }

        // Vertex spread (ddof=1 over 5 centroid distances).
        double scd = 0.0, cd[5];
#pragma unroll
        for (int v = 0; v < 5; ++v) {
            double c2 = fma(-0.4, S[v], h[gidx(v, v)]) + 0.04 * T;
            cd[v] = (c2 > 0.0) ? sqrt(c2) : 0.0;
            scd += cd[v];
        }
        double meanC = scd * 0.2;
        double vc = 0.0;
#pragma unroll
        for (int v = 0; v < 5; ++v) {
            double d = cd[v] - meanC;
            vc = fma(d, d, vc);
        }
        double spread = sqrt(vc * 0.25);

        // W[pq] = (x_p - x_0)·(x_q - x_0), p,q in 1..4 (PSD) ->
        // det M6 = -16 det W; volume^2 = det W / 576.
        double W[4][4];
#pragma unroll
        for (int pi = 0; pi < 4; ++pi)
#pragma unroll
            for (int qi = 0; qi < 4; ++qi) {
                int lo = (pi < qi ? pi : qi) + 1;
                int hi = (pi < qi ? qi : pi) + 1;
                W[pi][qi] = h[gidx(lo, hi)] - h[gidx(0, qi + 1)]
                          - h[gidx(0, pi + 1)] + h[gidx(0, 0)];
            }

        double det = 1.0;
#pragma unroll
        for (int k = 0; k < 4; ++k) {
            double pv = W[k][k];
            det *= pv;
            double inv = (pv != 0.0) ? 1.0 / pv : 0.0;
#pragma unroll
            for (int r = k + 1; r < 4; ++r) {
                double fac = W[r][k] * inv;
#pragma unroll
                for (int c = k + 1; c < 4; ++c)
                    W[r][c] = fma(-fac, W[k][c], W[r][c]);
            }
        }

        double v2 = det / 576.0;
        double volume = (v2 > 0.0) ? sqrt(v2) : 0.0;

        double vn = 1.0 / (1.0 + exp(-10.0 * volume));
        double er = 1.0 / (1.0 + exp(-(stdE / (meanE + 1e-6))));
        double sn = 1.0 / (1.0 + exp(-spread));

        double seed = 0.4 * vn + 0.3 * er + 0.3 * sn;
        seed = fmin(fmax(seed, 1e-6), 1.0 - 1e-6);
        double drift = (vn + er + sn) * 0.01;

        double x = seed, cv = 0.0, factor = 0.5;
#pragma unroll
        for (int k = 0; k < 8; ++k) {
            double xs = x * 3.0;
            double dg = floor(xs);
            double fr = xs - dg;
            cv += (dg == 2.0) ? factor : 0.0;
            factor *= 0.5;
            x = fmin(fmax(fr + drift, 1e-6), 1.0 - 1e-6);
        }
        cv = fmin(fmax(cv, 0.0), 1.0);

        if (item2 < nItems)
            __builtin_nontemporal_store((float)cv, &out[item2]);
    }
}

extern "C" void kernel_launch(void* const* d_in, const int* in_sizes, int n_in,
                              void* d_out, int out_size, void* d_ws, size_t ws_size,
                              hipStream_t stream) {
    const float* pent = (const float*)d_in[0];
    float* out = (float*)d_out;
    int nItems = in_sizes[0] / 640;            // 5*128 floats per item
    int blocks = (nItems + 31) / 32;           // 32 items per 256-thread block
    hipLaunchKernelGGL(fingerprint_kernel, dim3(blocks), dim3(256), 0, stream,
                       pent, out, nItems);
}